// Round 3
// baseline (477.238 us; speedup 1.0000x reference)
//
#include <hip/hip_runtime.h>
#include <hip/hip_bf16.h>
#include <stdint.h>

#define DIMV 1910
#define KP   1920                 // padded K — multiple of 64
#define NT   60                   // K tiles of 32
#define PHI_F  1.6180339887498949f
#define BETA_F 0.3819660112501051f

typedef __attribute__((ext_vector_type(4))) float f32x4;
typedef __attribute__((ext_vector_type(8))) short bf16x8;
typedef __attribute__((ext_vector_type(8))) unsigned short u16x8;

__device__ __forceinline__ void gl16(const void* g, void* l) {
    __builtin_amdgcn_global_load_lds(
        (const __attribute__((address_space(1))) void*)(uintptr_t)g,
        (__attribute__((address_space(3))) void*)(uint32_t)(uintptr_t)l,
        16, 0, 0);
}

__global__ void k_scatter(const int* __restrict__ ridx, const int* __restrict__ cidx,
                          const float* __restrict__ vals, float* __restrict__ Wd, int nz) {
    int i = blockIdx.x * 256 + threadIdx.x;
    if (i < nz) atomicAdd(Wd + (long)ridx[i] * DIMV + cidx[i], vals[i]);
}

// W' = W + PHI*I, [1920][1920] bf16 (rows 1920..2047 of the 2048-row alloc stay garbage:
// they only feed C columns >= 1920 which are never written)
__global__ void k_build_w(const float* __restrict__ Wd, unsigned short* __restrict__ Wb, int total8) {
    int stride = gridDim.x * blockDim.x;
    for (int i = blockIdx.x * blockDim.x + threadIdx.x; i < total8; i += stride) {
        int v = i * 8;
        int n = v / KP;
        int k = v - n * KP;
        u16x8 o;
#pragma unroll
        for (int j = 0; j < 8; ++j) {
            int kk = k + j;
            float fv = (n < DIMV && kk < DIMV) ? Wd[(size_t)n * DIMV + kk] : 0.f;
            if (kk == n && n < DIMV) fv += PHI_F;
            __hip_bfloat16 b = __float2bfloat16(fv);
            o[j] = *reinterpret_cast<unsigned short*>(&b);
        }
        *(u16x8*)(Wb + (size_t)v) = o;
    }
}

// x fp32 [M][1910] -> bf16 [M][1920]
__global__ void k_conv_x(const float* __restrict__ x, unsigned short* __restrict__ xb, int total8) {
    int stride = gridDim.x * blockDim.x;
    for (int i = blockIdx.x * blockDim.x + threadIdx.x; i < total8; i += stride) {
        int v = i * 8;
        int row = v / KP;
        int col = v - row * KP;
        u16x8 o;
        if (col + 8 <= DIMV) {
            const float2* s = (const float2*)(x + (size_t)row * DIMV + col);
            float2 f0 = s[0], f1 = s[1], f2 = s[2], f3 = s[3];
            float f[8] = {f0.x, f0.y, f1.x, f1.y, f2.x, f2.y, f3.x, f3.y};
#pragma unroll
            for (int j = 0; j < 8; ++j) {
                __hip_bfloat16 b = __float2bfloat16(f[j]);
                o[j] = *reinterpret_cast<unsigned short*>(&b);
            }
        } else {
#pragma unroll
            for (int j = 0; j < 8; ++j) {
                int c = col + j;
                float fv = (c < DIMV) ? x[(size_t)row * DIMV + c] : 0.f;
                __hip_bfloat16 b = __float2bfloat16(fv);
                o[j] = *reinterpret_cast<unsigned short*>(&b);
            }
        }
        *(u16x8*)(xb + (size_t)v) = o;
    }
}

// C[m][n] = BETA * sum_k A[m][k] * B[n][k]
// Tile 256x256, BK=32, 512 threads (8 waves: 2M x 4N), per-wave 128x64 (8x4 frags).
// LDS: 3-buf x (A 16KB + B 16KB) = 96KB. Stage distance 2, counted vmcnt(4)/tile.
// Swizzle: 4 16B-slots/row, phys_slot = logical ^ ((row>>1)&3) -> 2-way max (free).
__global__ __launch_bounds__(512, 2) void k_gemm(const short* __restrict__ A,
                                                 const short* __restrict__ B,
                                                 float* __restrict__ C) {
    __shared__ short As[3 * 256 * 32];   // 48 KB
    __shared__ short Bs[3 * 256 * 32];   // 48 KB

    const int bid = blockIdx.x;
    const int bn  = bid & 7;             // XCD-pinned N column (B panel ~1MB in its L2)
    const int bm  = bid >> 3;

    const int tid = threadIdx.x;
    const int w   = tid >> 6;
    const int l   = tid & 63;
    const int wm  = w >> 2;              // 0..1 (M)
    const int wn  = w & 3;               // 0..3 (N)
    const int fr  = l & 15;
    const int q   = l >> 4;              // 0..3

    // ---- staging (pre-swizzled global source, linear LDS dest) ----
    const int srow  = tid >> 2;                        // 0..127
    const int lslot = (tid & 3) ^ ((tid >> 3) & 3);    // logical 16B slot for this lane
    const char* aG = (const char*)A + ((size_t)(bm * 256 + srow) * KP) * 2 + lslot * 16;
    const char* bG = (const char*)B + ((size_t)(bn * 256 + srow) * KP) * 2 + lslot * 16;
    const size_t gstep = (size_t)128 * KP * 2;         // 128 global rows
    char* aL0 = (char*)As + tid * 16;
    char* bL0 = (char*)Bs + tid * 16;

    // ---- fragment read bases (swizzled) ----
    const int co    = (q ^ ((fr >> 1) & 3)) * 16;      // swizzled slot byte offset
    const int aBase = (wm * 128 + fr) * 64 + co;
    const int bBase = (wn * 64  + fr) * 64 + co;

    f32x4 acc[8][4] = {};

    // ---- prologue: stage tiles 0,1 (8 loads/thread), wait tile 0 (oldest 4) ----
#pragma unroll
    for (int tt = 0; tt < 2; ++tt) {
        const char* ga = aG + tt * 64;
        const char* gb = bG + tt * 64;
        char* la = aL0 + tt * 16384;
        char* lb = bL0 + tt * 16384;
        gl16(ga, la); gl16(ga + gstep, la + 8192);
        gl16(gb, lb); gl16(gb + gstep, lb + 8192);
    }
    asm volatile("s_waitcnt vmcnt(4)" ::: "memory");
    __builtin_amdgcn_s_barrier();
    asm volatile("" ::: "memory");

    int rdo = 0;                 // read buffer byte offset  (t%3)*16384
    int sto = 2 * 16384;         // stage buffer byte offset ((t+2)%3)*16384

#pragma unroll 3
    for (int t = 0; t < NT; ++t) {
        const char* pa = (const char*)As + rdo + aBase;
        const char* pb = (const char*)Bs + rdo + bBase;

        // ---- P1: ds_read A(8) + B(ni 0,1); stage A(t+2); MFMA ni 0,1 ----
        bf16x8 af[8], b01[2];
#pragma unroll
        for (int mi = 0; mi < 8; ++mi) af[mi] = *(const bf16x8*)(pa + mi * 1024);
#pragma unroll
        for (int ni = 0; ni < 2; ++ni) b01[ni] = *(const bf16x8*)(pb + ni * 1024);
        if (t + 2 < NT) {
            const char* g = aG + (size_t)(t + 2) * 64;
            gl16(g, aL0 + sto); gl16(g + gstep, aL0 + sto + 8192);
        }
        asm volatile("" ::: "memory");
        __builtin_amdgcn_s_barrier();
        asm volatile("" ::: "memory");
        __builtin_amdgcn_s_setprio(1);
#pragma unroll
        for (int mi = 0; mi < 8; ++mi)
#pragma unroll
            for (int ni = 0; ni < 2; ++ni)
                acc[mi][ni] = __builtin_amdgcn_mfma_f32_16x16x32_bf16(af[mi], b01[ni], acc[mi][ni], 0, 0, 0);
        __builtin_amdgcn_s_setprio(0);
        asm volatile("" ::: "memory");
        __builtin_amdgcn_s_barrier();
        asm volatile("" ::: "memory");

        // ---- P2: ds_read B(ni 2,3); stage B(t+2); counted vmcnt; MFMA ni 2,3 ----
        bf16x8 b23[2];
#pragma unroll
        for (int ni = 0; ni < 2; ++ni) b23[ni] = *(const bf16x8*)(pb + (ni + 2) * 1024);
        if (t + 2 < NT) {
            const char* g = bG + (size_t)(t + 2) * 64;
            gl16(g, bL0 + sto); gl16(g + gstep, bL0 + sto + 8192);
            // tile t+1's 4 loads must land; tile t+2's 4 stay in flight
            asm volatile("s_waitcnt vmcnt(4)" ::: "memory");
        } else {
            asm volatile("s_waitcnt vmcnt(0)" ::: "memory");
        }
        __builtin_amdgcn_s_barrier();
        asm volatile("" ::: "memory");
        __builtin_amdgcn_s_setprio(1);
#pragma unroll
        for (int mi = 0; mi < 8; ++mi)
#pragma unroll
            for (int ni = 0; ni < 2; ++ni)
                acc[mi][ni + 2] = __builtin_amdgcn_mfma_f32_16x16x32_bf16(af[mi], b23[ni], acc[mi][ni + 2], 0, 0, 0);
        __builtin_amdgcn_s_setprio(0);
        asm volatile("" ::: "memory");
        __builtin_amdgcn_s_barrier();
        asm volatile("" ::: "memory");

        rdo += 16384; if (rdo == 49152) rdo = 0;
        sto += 16384; if (sto == 49152) sto = 0;
    }

    // ---- epilogue: C/D frag row = q*4 + r, col = fr (m89-verified) ----
    const int grow0 = bm * 256 + wm * 128 + q * 4;
    const int gcol0 = bn * 256 + wn * 64 + fr;
#pragma unroll
    for (int mi = 0; mi < 8; ++mi) {
#pragma unroll
        for (int ni = 0; ni < 4; ++ni) {
            int gcol = gcol0 + ni * 16;
            if (gcol < DIMV) {
                size_t base = (size_t)(grow0 + mi * 16) * DIMV + gcol;
#pragma unroll
                for (int r = 0; r < 4; ++r)
                    C[base + (size_t)r * DIMV] = BETA_F * acc[mi][ni][r];
            }
        }
    }
}

extern "C" void kernel_launch(void* const* d_in, const int* in_sizes, int n_in,
                              void* d_out, int out_size, void* d_ws, size_t ws_size,
                              hipStream_t stream) {
    const float* x    = (const float*)d_in[0];
    const int*   widx = (const int*)d_in[1];
    const float* wval = (const float*)d_in[2];
    float* out = (float*)d_out;

    const int nz = in_sizes[2];
    const int M  = in_sizes[0] / DIMV;      // 32768

    const size_t xb_bytes = (size_t)M * KP * 2;          // 125,829,120
    const size_t wb_bytes = (size_t)2048 * KP * 2;       //   7,864,320 (2048 rows; 1920+ garbage ok)
    const size_t wd_bytes = (size_t)DIMV * DIMV * 4;     //  14,592,400
    char* ws = (char*)d_ws;
    unsigned short* xb = (unsigned short*)ws;
    unsigned short* Wb = (unsigned short*)(ws + xb_bytes);
    float*          Wd = (float*)ws;        // aliased into xb region: dead before conv_x runs
    if (ws_size < xb_bytes + wb_bytes) return;
    (void)wd_bytes;

    hipMemsetAsync(Wd, 0, wd_bytes, stream);
    k_scatter<<<(nz + 255) / 256, 256, 0, stream>>>(widx, widx + nz, wval, Wd, nz);
    k_build_w<<<1800, 256, 0, stream>>>(Wd, Wb, KP * KP / 8);
    k_conv_x<<<2048, 256, 0, stream>>>(x, xb, M * KP / 8);
    k_gemm<<<1024, 512, 0, stream>>>((const short*)xb, (const short*)Wb, out);
}

// Round 4
// 473.687 us; speedup vs baseline: 1.0075x; 1.0075x over previous
//
#include <hip/hip_runtime.h>
#include <hip/hip_bf16.h>
#include <stdint.h>

#define DIMV 1910
#define KP   1920                 // padded K — multiple of 64
#define NT   30                   // K tiles of 64
#define PHI_F  1.6180339887498949f
#define BETA_F 0.3819660112501051f

typedef __attribute__((ext_vector_type(4))) float f32x4;
typedef __attribute__((ext_vector_type(8))) short bf16x8;
typedef __attribute__((ext_vector_type(8))) unsigned short u16x8;

__device__ __forceinline__ void gl16(const void* g, void* l) {
    __builtin_amdgcn_global_load_lds(
        (const __attribute__((address_space(1))) void*)(uintptr_t)g,
        (__attribute__((address_space(3))) void*)(uint32_t)(uintptr_t)l,
        16, 0, 0);
}

__global__ void k_scatter(const int* __restrict__ ridx, const int* __restrict__ cidx,
                          const float* __restrict__ vals, float* __restrict__ Wd, int nz) {
    int i = blockIdx.x * 256 + threadIdx.x;
    if (i < nz) atomicAdd(Wd + (long)ridx[i] * DIMV + cidx[i], vals[i]);
}

// W' = W + PHI*I, [1920][1920] bf16 (rows 1920..2047 of the 2048-row alloc stay garbage:
// they only feed C columns >= 1920 which are never written)
__global__ void k_build_w(const float* __restrict__ Wd, unsigned short* __restrict__ Wb, int total8) {
    int stride = gridDim.x * blockDim.x;
    for (int i = blockIdx.x * blockDim.x + threadIdx.x; i < total8; i += stride) {
        int v = i * 8;
        int n = v / KP;
        int k = v - n * KP;
        u16x8 o;
#pragma unroll
        for (int j = 0; j < 8; ++j) {
            int kk = k + j;
            float fv = (n < DIMV && kk < DIMV) ? Wd[(size_t)n * DIMV + kk] : 0.f;
            if (kk == n && n < DIMV) fv += PHI_F;
            __hip_bfloat16 b = __float2bfloat16(fv);
            o[j] = *reinterpret_cast<unsigned short*>(&b);
        }
        *(u16x8*)(Wb + (size_t)v) = o;
    }
}

// x fp32 [M][1910] -> bf16 [M][1920]
__global__ void k_conv_x(const float* __restrict__ x, unsigned short* __restrict__ xb, int total8) {
    int stride = gridDim.x * blockDim.x;
    for (int i = blockIdx.x * blockDim.x + threadIdx.x; i < total8; i += stride) {
        int v = i * 8;
        int row = v / KP;
        int col = v - row * KP;
        u16x8 o;
        if (col + 8 <= DIMV) {
            const float2* s = (const float2*)(x + (size_t)row * DIMV + col);
            float2 f0 = s[0], f1 = s[1], f2 = s[2], f3 = s[3];
            float f[8] = {f0.x, f0.y, f1.x, f1.y, f2.x, f2.y, f3.x, f3.y};
#pragma unroll
            for (int j = 0; j < 8; ++j) {
                __hip_bfloat16 b = __float2bfloat16(f[j]);
                o[j] = *reinterpret_cast<unsigned short*>(&b);
            }
        } else {
#pragma unroll
            for (int j = 0; j < 8; ++j) {
                int c = col + j;
                float fv = (c < DIMV) ? x[(size_t)row * DIMV + c] : 0.f;
                __hip_bfloat16 b = __float2bfloat16(fv);
                o[j] = *reinterpret_cast<unsigned short*>(&b);
            }
        }
        *(u16x8*)(xb + (size_t)v) = o;
    }
}

// C[m][n] = BETA * sum_k A[m][k] * B[n][k]
// Tile 256x256, BK=64, 512 threads (8 waves: 2M x 4N), per-wave 128x64.
// m201-style 4-quadrant phases per K-tile, 2 LDS buffers (128KB), stage-next
// interleaved 3/3/2 gl16, vmcnt(0) once per tile with >=1-phase lead.
// LDS row = 128B = 8 16B-slots, phys_slot = logical ^ (row&7) (G4 swizzle),
// inverse applied on the global source (rule 21).
__global__ __launch_bounds__(512, 2) void k_gemm(const short* __restrict__ A,
                                                 const short* __restrict__ B,
                                                 float* __restrict__ C) {
    __shared__ char lds[131072];   // 2 x (A 32KB + B 32KB)

    const int bid = blockIdx.x;
    const int bn  = bid & 7;             // XCD-pinned N column
    const int bm  = bid >> 3;

    const int tid = threadIdx.x;
    const int w   = tid >> 6;
    const int l   = tid & 63;
    const int wm  = w >> 2;              // 0..1 (M)
    const int wn  = w & 3;               // 0..3 (N)
    const int fr  = l & 15;
    const int q   = l >> 4;              // 0..3

    // ---- staging source (pre-swizzled), linear LDS dest ----
    const int    rs   = tid >> 3;                       // row within a 64-row sweep
    const size_t KPB  = (size_t)KP * 2;                 // 3840 bytes/row
    const char*  aSrc = (const char*)A + (size_t)(bm * 256 + rs) * KPB + (((tid & 7) ^ (rs & 7)) * 16);
    const char*  bSrc = (const char*)B + (size_t)(bn * 256 + rs) * KPB + (((tid & 7) ^ (rs & 7)) * 16);
    char* stDst = lds + tid * 16;

    // ---- fragment read offsets (swizzled slots) ----
    const int co0  = ((q    ) ^ (fr & 7)) * 16;         // kk=0
    const int co1  = ((4 + q) ^ (fr & 7)) * 16;         // kk=1
    const int aOff = (wm * 128 + fr) * 128;             // + mh*8192 + mi*2048
    const int bOff = 32768 + (wn * 64 + fr) * 128;      // + nh*4096 + ni*2048

    f32x4 acc[8][4] = {};

#define STAGE_A(tt, bo, s) gl16(aSrc + (size_t)(s) * 64 * KPB + (size_t)(tt) * 128, stDst + (bo) + (s) * 8192)
#define STAGE_B(tt, bo, s) gl16(bSrc + (size_t)(s) * 64 * KPB + (size_t)(tt) * 128, stDst + (bo) + 32768 + (s) * 8192)

    // ---- prologue: stage tile 0 -> buf0, drain, barrier ----
#pragma unroll
    for (int s = 0; s < 4; ++s) STAGE_A(0, 0, s);
#pragma unroll
    for (int s = 0; s < 4; ++s) STAGE_B(0, 0, s);
    asm volatile("s_waitcnt vmcnt(0)" ::: "memory");
    __builtin_amdgcn_s_barrier();
    asm volatile("" ::: "memory");

    int bo = 0;
    for (int t = 0; t < NT; ++t) {
        const int nbo = bo ^ 65536;
        const char* pa = lds + bo + aOff;
        const char* pb = lds + bo + bOff;
        const bool st = (t + 1 < NT);
        bf16x8 a[4][2], b[2][2];

        // ======== qd0: (mh=0, nh=0) — 12 reads, stage A0-2 ========
#pragma unroll
        for (int mi = 0; mi < 4; ++mi) {
            a[mi][0] = *(const bf16x8*)(pa + mi * 2048 + co0);
            a[mi][1] = *(const bf16x8*)(pa + mi * 2048 + co1);
        }
#pragma unroll
        for (int ni = 0; ni < 2; ++ni) {
            b[ni][0] = *(const bf16x8*)(pb + ni * 2048 + co0);
            b[ni][1] = *(const bf16x8*)(pb + ni * 2048 + co1);
        }
        if (st) { STAGE_A(t + 1, nbo, 0); STAGE_A(t + 1, nbo, 1); STAGE_A(t + 1, nbo, 2); }
        asm volatile("s_waitcnt lgkmcnt(8)" ::: "memory");
        __builtin_amdgcn_s_barrier();
        asm volatile("s_waitcnt lgkmcnt(0)" ::: "memory");
        __builtin_amdgcn_sched_barrier(0);
        __builtin_amdgcn_s_setprio(1);
#pragma unroll
        for (int kk = 0; kk < 2; ++kk)
#pragma unroll
            for (int mi = 0; mi < 4; ++mi)
#pragma unroll
                for (int ni = 0; ni < 2; ++ni)
                    acc[mi][ni] = __builtin_amdgcn_mfma_f32_16x16x32_bf16(a[mi][kk], b[ni][kk], acc[mi][ni], 0, 0, 0);
        __builtin_amdgcn_s_setprio(0);
        asm volatile("" ::: "memory");
        __builtin_amdgcn_s_barrier();
        asm volatile("" ::: "memory");

        // ======== qd1: (mh=0, nh=1) — 4 reads, stage A3,B0,B1 ========
#pragma unroll
        for (int ni = 0; ni < 2; ++ni) {
            b[ni][0] = *(const bf16x8*)(pb + 4096 + ni * 2048 + co0);
            b[ni][1] = *(const bf16x8*)(pb + 4096 + ni * 2048 + co1);
        }
        if (st) { STAGE_A(t + 1, nbo, 3); STAGE_B(t + 1, nbo, 0); STAGE_B(t + 1, nbo, 1); }
        asm volatile("" ::: "memory");
        __builtin_amdgcn_s_barrier();
        asm volatile("s_waitcnt lgkmcnt(0)" ::: "memory");
        __builtin_amdgcn_sched_barrier(0);
        __builtin_amdgcn_s_setprio(1);
#pragma unroll
        for (int kk = 0; kk < 2; ++kk)
#pragma unroll
            for (int mi = 0; mi < 4; ++mi)
#pragma unroll
                for (int ni = 0; ni < 2; ++ni)
                    acc[mi][ni + 2] = __builtin_amdgcn_mfma_f32_16x16x32_bf16(a[mi][kk], b[ni][kk], acc[mi][ni + 2], 0, 0, 0);
        __builtin_amdgcn_s_setprio(0);
        asm volatile("" ::: "memory");
        __builtin_amdgcn_s_barrier();
        asm volatile("" ::: "memory");

        // ======== qd2: (mh=1, nh=1) — 8 reads, stage B2,B3 ========
#pragma unroll
        for (int mi = 0; mi < 4; ++mi) {
            a[mi][0] = *(const bf16x8*)(pa + 8192 + mi * 2048 + co0);
            a[mi][1] = *(const bf16x8*)(pa + 8192 + mi * 2048 + co1);
        }
        if (st) { STAGE_B(t + 1, nbo, 2); STAGE_B(t + 1, nbo, 3); }
        asm volatile("" ::: "memory");
        __builtin_amdgcn_s_barrier();
        asm volatile("s_waitcnt lgkmcnt(0)" ::: "memory");
        __builtin_amdgcn_sched_barrier(0);
        __builtin_amdgcn_s_setprio(1);
#pragma unroll
        for (int kk = 0; kk < 2; ++kk)
#pragma unroll
            for (int mi = 0; mi < 4; ++mi)
#pragma unroll
                for (int ni = 0; ni < 2; ++ni)
                    acc[mi + 4][ni + 2] = __builtin_amdgcn_mfma_f32_16x16x32_bf16(a[mi][kk], b[ni][kk], acc[mi + 4][ni + 2], 0, 0, 0);
        __builtin_amdgcn_s_setprio(0);
        asm volatile("" ::: "memory");
        __builtin_amdgcn_s_barrier();
        asm volatile("" ::: "memory");

        // ======== qd3: (mh=1, nh=0) — 4 reads (B0 re-read), vmcnt after MFMA ========
#pragma unroll
        for (int ni = 0; ni < 2; ++ni) {
            b[ni][0] = *(const bf16x8*)(pb + ni * 2048 + co0);
            b[ni][1] = *(const bf16x8*)(pb + ni * 2048 + co1);
        }
        asm volatile("" ::: "memory");
        __builtin_amdgcn_s_barrier();
        asm volatile("s_waitcnt lgkmcnt(0)" ::: "memory");
        __builtin_amdgcn_sched_barrier(0);
        __builtin_amdgcn_s_setprio(1);
#pragma unroll
        for (int kk = 0; kk < 2; ++kk)
#pragma unroll
            for (int mi = 0; mi < 4; ++mi)
#pragma unroll
                for (int ni = 0; ni < 2; ++ni)
                    acc[mi + 4][ni] = __builtin_amdgcn_mfma_f32_16x16x32_bf16(a[mi][kk], b[ni][kk], acc[mi + 4][ni], 0, 0, 0);
        __builtin_amdgcn_s_setprio(0);
        // next tile's staged loads must be in LDS before its qd0 reads
        asm volatile("s_waitcnt vmcnt(0)" ::: "memory");
        __builtin_amdgcn_s_barrier();
        asm volatile("" ::: "memory");

        bo = nbo;
    }
#undef STAGE_A
#undef STAGE_B

    // ---- epilogue: C/D frag row = q*4 + r, col = fr (m89-verified) ----
    const int grow0 = bm * 256 + wm * 128 + q * 4;
    const int gcol0 = bn * 256 + wn * 64 + fr;
#pragma unroll
    for (int mi = 0; mi < 8; ++mi) {
#pragma unroll
        for (int ni = 0; ni < 4; ++ni) {
            int gcol = gcol0 + ni * 16;
            if (gcol < DIMV) {
                size_t base = (size_t)(grow0 + mi * 16) * DIMV + gcol;
#pragma unroll
                for (int r = 0; r < 4; ++r)
                    C[base + (size_t)r * DIMV] = BETA_F * acc[mi][ni][r];
            }
        }
    }
}

extern "C" void kernel_launch(void* const* d_in, const int* in_sizes, int n_in,
                              void* d_out, int out_size, void* d_ws, size_t ws_size,
                              hipStream_t stream) {
    const float* x    = (const float*)d_in[0];
    const int*   widx = (const int*)d_in[1];
    const float* wval = (const float*)d_in[2];
    float* out = (float*)d_out;

    const int nz = in_sizes[2];
    const int M  = in_sizes[0] / DIMV;      // 32768

    const size_t xb_bytes = (size_t)M * KP * 2;          // 125,829,120
    const size_t wb_bytes = (size_t)2048 * KP * 2;       //   7,864,320
    const size_t wd_bytes = (size_t)DIMV * DIMV * 4;     //  14,592,400
    char* ws = (char*)d_ws;
    unsigned short* xb = (unsigned short*)ws;
    unsigned short* Wb = (unsigned short*)(ws + xb_bytes);
    float*          Wd = (float*)ws;        // aliased into xb region: dead before conv_x runs
    if (ws_size < xb_bytes + wb_bytes) return;
    (void)wd_bytes;

    hipMemsetAsync(Wd, 0, wd_bytes, stream);
    k_scatter<<<(nz + 255) / 256, 256, 0, stream>>>(widx, widx + nz, wval, Wd, nz);
    k_build_w<<<1800, 256, 0, stream>>>(Wd, Wb, KP * KP / 8);
    k_conv_x<<<2048, 256, 0, stream>>>(x, xb, M * KP / 8);
    k_gemm<<<1024, 512, 0, stream>>>((const short*)xb, (const short*)Wb, out);
}